// Round 4
// baseline (117.491 us; speedup 1.0000x reference)
//
#include <hip/hip_runtime.h>

#define NPIX 16384   // B*HW
#define LCTX 32
#define DIM  128
#define SCALE 0.125f // 64^-0.5

// ---------------------------------------------------------------------------
// K0: fold weights.
//   Ms[e][j] (j = h*128+c) = SCALE * sum_d Wq[e][h*64+d] * Wkv[c][h*64+d]
//   Nf[i][j] (i = h*128+c) = sum_d Wkv[c][128+h*64+d] * Wo[h*64+d][j]
// ---------------------------------------------------------------------------
__global__ __launch_bounds__(256)
void fold_kernel(const float* __restrict__ Wq, const float* __restrict__ Wkv,
                 const float* __restrict__ Wo,
                 float* __restrict__ Ms, float* __restrict__ Nf)
{
    const int t = threadIdx.x;
    const int b = blockIdx.x;
    if (b < 128) {
        const int e = b, h = t >> 7, c = t & 127;
        const float4* q4p = reinterpret_cast<const float4*>(Wq + e * 128 + h * 64);
        const float4* k4p = reinterpret_cast<const float4*>(Wkv + c * 256 + h * 64);
        float acc = 0.f;
        #pragma unroll
        for (int d4 = 0; d4 < 16; ++d4) {
            const float4 a = q4p[d4], k = k4p[d4];
            acc += a.x * k.x + a.y * k.y + a.z * k.z + a.w * k.w;
        }
        Ms[e * 256 + t] = SCALE * acc;
    } else {
        const int b2 = b - 128;
        const int i = b2 * 2 + (t >> 7), j = t & 127;
        const int h = i >> 7, c = i & 127;
        const float4* v4p = reinterpret_cast<const float4*>(Wkv + c * 256 + 128 + h * 64);
        float acc = 0.f;
        #pragma unroll
        for (int d4 = 0; d4 < 16; ++d4) {
            const float4 v4 = v4p[d4];
            acc += v4.x * Wo[(h * 64 + d4 * 4 + 0) * 128 + j];
            acc += v4.y * Wo[(h * 64 + d4 * 4 + 1) * 128 + j];
            acc += v4.z * Wo[(h * 64 + d4 * 4 + 2) * 128 + j];
            acc += v4.w * Wo[(h * 64 + d4 * 4 + 3) * 128 + j];
        }
        Nf[i * 128 + j] = acc;
    }
}

// ---------------------------------------------------------------------------
// Fused kernel: qk -> online-softmax attn -> out.  4 waves/block, 4 px/wave.
// Lane = (h, c0): owns QK/ctxw float4 at column h*128 + c0*4.
// One __syncthreads (after x staging); everything else wave-synchronous.
// ---------------------------------------------------------------------------
__global__ __launch_bounds__(256, 4)
void fused_kernel(const float* __restrict__ x, const float* __restrict__ ctx,
                  const float* __restrict__ Ms, const float* __restrict__ Nf,
                  const float* __restrict__ bo, float* __restrict__ out)
{
    __shared__ float xs[16 * 128];   //  8 KB: x tile (16 px)
    __shared__ float cs[16 * 256];   // 16 KB: ctxw tile (wave-private slices)

    const int t = threadIdx.x;
    const int w = t >> 6, lane = t & 63;
    const int c0 = lane & 31;        // float4 column within 128-group
    const int lh = lane >> 5;        // head
    const int pxbase = blockIdx.x * 16;      // block's first pixel
    const int wpx = pxbase + w * 4;          // wave's first pixel

    // ---- stage x tile (coalesced) ----
    #pragma unroll
    for (int k = 0; k < 2; ++k)
        reinterpret_cast<float4*>(xs)[t + k * 256] =
            reinterpret_cast<const float4*>(x + (size_t)pxbase * DIM)[t + k * 256];
    __syncthreads();

    // ---- Phase 1: qk4[p] = (x[wpx+p] . Ms[:, j4..j4+3]),  j4 = lh*128+c0*4 ----
    float4 qk4[4];
    #pragma unroll
    for (int p = 0; p < 4; ++p) qk4[p] = make_float4(0.f, 0.f, 0.f, 0.f);
    {
        const float4* ms4 = reinterpret_cast<const float4*>(Ms) + (lh * 32 + c0);
        const float4* xw  = reinterpret_cast<const float4*>(xs + (w * 4) * DIM);
        for (int e4 = 0; e4 < 32; ++e4) {
            float4 xv[4];
            #pragma unroll
            for (int p = 0; p < 4; ++p) xv[p] = xw[p * 32 + e4];
            #pragma unroll
            for (int d = 0; d < 4; ++d) {
                const float4 m4 = ms4[(e4 * 4 + d) * 64];
                #pragma unroll
                for (int p = 0; p < 4; ++p) {
                    const float xe = (d == 0) ? xv[p].x : (d == 1) ? xv[p].y
                                   : (d == 2) ? xv[p].z : xv[p].w;
                    qk4[p].x += xe * m4.x; qk4[p].y += xe * m4.y;
                    qk4[p].z += xe * m4.z; qk4[p].w += xe * m4.w;
                }
            }
        }
    }

    // ---- Phase 2: online-softmax attention, 4 interleaved pixel chains ----
    float m[4], dn[4];
    float4 acc[4];
    #pragma unroll
    for (int p = 0; p < 4; ++p) {
        m[p] = -3.0e38f; dn[p] = 0.f;
        acc[p] = make_float4(0.f, 0.f, 0.f, 0.f);
    }
    {
        const float4* cb0 = reinterpret_cast<const float4*>(ctx + (size_t)(wpx + 0) * LCTX * DIM) + c0;
        const float4* cb1 = reinterpret_cast<const float4*>(ctx + (size_t)(wpx + 1) * LCTX * DIM) + c0;
        const float4* cb2 = reinterpret_cast<const float4*>(ctx + (size_t)(wpx + 2) * LCTX * DIM) + c0;
        const float4* cb3 = reinterpret_cast<const float4*>(ctx + (size_t)(wpx + 3) * LCTX * DIM) + c0;
        #pragma unroll 4
        for (int r = 0; r < LCTX; ++r) {
            float4 cv[4];
            cv[0] = cb0[r * 32]; cv[1] = cb1[r * 32];
            cv[2] = cb2[r * 32]; cv[3] = cb3[r * 32];
            float part[4];
            #pragma unroll
            for (int p = 0; p < 4; ++p)
                part[p] = cv[p].x * qk4[p].x + cv[p].y * qk4[p].y
                        + cv[p].z * qk4[p].z + cv[p].w * qk4[p].w;
            #pragma unroll
            for (int off = 16; off >= 1; off >>= 1) {
                #pragma unroll
                for (int p = 0; p < 4; ++p) part[p] += __shfl_xor(part[p], off);
            }
            #pragma unroll
            for (int p = 0; p < 4; ++p) {
                const float mn = fmaxf(m[p], part[p]);
                const float sc = __expf(m[p] - mn);
                const float er = __expf(part[p] - mn);
                dn[p] = dn[p] * sc + er;
                acc[p].x = acc[p].x * sc + er * cv[p].x;
                acc[p].y = acc[p].y * sc + er * cv[p].y;
                acc[p].z = acc[p].z * sc + er * cv[p].z;
                acc[p].w = acc[p].w * sc + er * cv[p].w;
                m[p] = mn;
            }
        }
    }
    // normalize + write ctxw to wave-private LDS slice
    {
        float* csw = cs + (w * 4) * 256;
        #pragma unroll
        for (int p = 0; p < 4; ++p) {
            const float inv = 1.f / dn[p];
            float4 r = acc[p];
            r.x *= inv; r.y *= inv; r.z *= inv; r.w *= inv;
            reinterpret_cast<float4*>(csw + p * 256)[lh * 32 + c0] = r;
        }
    }
    // same-wave LDS dependency only: no barrier (lgkmcnt ordering suffices)

    // ---- Phase 3: out[px][j] = ctxw[px] . Nf[:,j] + bo[j] ----
    {
        const int jq = lane & 31;        // output float4 column
        const int ph = lane >> 5;        // pixel pair selector within wave
        const float4* csv0 = reinterpret_cast<const float4*>(cs + (w * 4 + ph * 2 + 0) * 256);
        const float4* csv1 = reinterpret_cast<const float4*>(cs + (w * 4 + ph * 2 + 1) * 256);
        const float4* nf4 = reinterpret_cast<const float4*>(Nf) + jq;
        float4 o0 = make_float4(0.f, 0.f, 0.f, 0.f);
        float4 o1 = make_float4(0.f, 0.f, 0.f, 0.f);
        #pragma unroll 4
        for (int i4 = 0; i4 < 64; ++i4) {
            const float4 a0 = csv0[i4];
            const float4 a1 = csv1[i4];
            #pragma unroll
            for (int d = 0; d < 4; ++d) {
                const float4 n4 = nf4[(i4 * 4 + d) * 32];
                const float a0e = (d == 0) ? a0.x : (d == 1) ? a0.y : (d == 2) ? a0.z : a0.w;
                const float a1e = (d == 0) ? a1.x : (d == 1) ? a1.y : (d == 2) ? a1.z : a1.w;
                o0.x += a0e * n4.x; o0.y += a0e * n4.y; o0.z += a0e * n4.z; o0.w += a0e * n4.w;
                o1.x += a1e * n4.x; o1.y += a1e * n4.y; o1.z += a1e * n4.z; o1.w += a1e * n4.w;
            }
        }
        const float4 b4 = reinterpret_cast<const float4*>(bo)[jq];
        o0.x += b4.x; o0.y += b4.y; o0.z += b4.z; o0.w += b4.w;
        o1.x += b4.x; o1.y += b4.y; o1.z += b4.z; o1.w += b4.w;
        reinterpret_cast<float4*>(out + (size_t)(wpx + ph * 2 + 0) * DIM)[jq] = o0;
        reinterpret_cast<float4*>(out + (size_t)(wpx + ph * 2 + 1) * DIM)[jq] = o1;
    }
}

// ---------------------------------------------------------------------------
// Fallback: round-1 fused kernel (used only if ws_size is too small).
// ---------------------------------------------------------------------------
#define PPB 8
__global__ __launch_bounds__(256, 4)
void ppca_kernel(const float* __restrict__ x, const float* __restrict__ ctx,
                 const float* __restrict__ Wq, const float* __restrict__ Wkv,
                 const float* __restrict__ Wo, const float* __restrict__ bo,
                 float* __restrict__ out)
{
    __shared__ float smem[4096];
    float* xs    = smem;
    float* qs    = smem + 1024;
    float* qks   = smem + 2048;
    float* attns = smem;
    float* ctxws = smem + 2048;
    float* outs  = smem + 1024;

    const int t = threadIdx.x;
    const int gbase = blockIdx.x * PPB;

    reinterpret_cast<float4*>(xs)[t] =
        reinterpret_cast<const float4*>(x + (size_t)gbase * DIM)[t];
    __syncthreads();

    {
        const int j = t & 127, pg = t >> 7;
        float acc[4] = {0.f, 0.f, 0.f, 0.f};
        for (int k = 0; k < 32; ++k) {
            const float w0 = Wq[(4*k + 0) * DIM + j];
            const float w1 = Wq[(4*k + 1) * DIM + j];
            const float w2 = Wq[(4*k + 2) * DIM + j];
            const float w3 = Wq[(4*k + 3) * DIM + j];
            #pragma unroll
            for (int pp = 0; pp < 4; ++pp) {
                const float4 xv = reinterpret_cast<const float4*>(xs + (pg*4 + pp) * DIM)[k];
                acc[pp] += xv.x*w0 + xv.y*w1 + xv.z*w2 + xv.w*w3;
            }
        }
        #pragma unroll
        for (int pp = 0; pp < 4; ++pp) qs[(pg*4 + pp) * DIM + j] = acc[pp];
    }
    __syncthreads();

    {
        const int c = t & 127, h = t >> 7;
        float acc[PPB] = {0.f,0.f,0.f,0.f,0.f,0.f,0.f,0.f};
        const float4* wrow = reinterpret_cast<const float4*>(Wkv + c * 256 + h * 64);
        for (int k = 0; k < 16; ++k) {
            const float4 w4 = wrow[k];
            #pragma unroll
            for (int p = 0; p < PPB; ++p) {
                const float4 q4 = reinterpret_cast<const float4*>(qs + p * DIM + h * 64)[k];
                acc[p] += q4.x*w4.x + q4.y*w4.y + q4.z*w4.z + q4.w*w4.w;
            }
        }
        #pragma unroll
        for (int p = 0; p < PPB; ++p) qks[(p*2 + h) * DIM + c] = acc[p];
    }
    __syncthreads();

    {
        const int l = t & 31, p = t >> 5;
        const float4* cr = reinterpret_cast<const float4*>(ctx + ((size_t)(gbase + p) * LCTX + l) * DIM);
        const float4* q0 = reinterpret_cast<const float4*>(qks + (p*2 + 0) * DIM);
        const float4* q1 = reinterpret_cast<const float4*>(qks + (p*2 + 1) * DIM);
        float s0 = 0.f, s1 = 0.f;
        #pragma unroll 8
        for (int k = 0; k < 32; ++k) {
            const float4 cv = cr[k], a = q0[k], b = q1[k];
            s0 += cv.x*a.x + cv.y*a.y + cv.z*a.z + cv.w*a.w;
            s1 += cv.x*b.x + cv.y*b.y + cv.z*b.z + cv.w*b.w;
        }
        s0 *= SCALE; s1 *= SCALE;
        float m0 = s0, m1 = s1;
        #pragma unroll
        for (int off = 16; off >= 1; off >>= 1) {
            m0 = fmaxf(m0, __shfl_xor(m0, off));
            m1 = fmaxf(m1, __shfl_xor(m1, off));
        }
        const float e0 = __expf(s0 - m0), e1 = __expf(s1 - m1);
        float d0 = e0, d1 = e1;
        #pragma unroll
        for (int off = 16; off >= 1; off >>= 1) {
            d0 += __shfl_xor(d0, off);
            d1 += __shfl_xor(d1, off);
        }
        attns[(p*2 + 0) * LCTX + l] = e0 / d0;
        attns[(p*2 + 1) * LCTX + l] = e1 / d1;
    }
    __syncthreads();

    {
        const int c = t & 127, pg = t >> 7;
        #pragma unroll
        for (int pp = 0; pp < 4; ++pp) {
            const int p = pg*4 + pp;
            const float* cb = ctx + (size_t)(gbase + p) * LCTX * DIM + c;
            const float4* a0p = reinterpret_cast<const float4*>(attns + (p*2 + 0) * LCTX);
            const float4* a1p = reinterpret_cast<const float4*>(attns + (p*2 + 1) * LCTX);
            float s0 = 0.f, s1 = 0.f;
            #pragma unroll
            for (int q = 0; q < 8; ++q) {
                const float4 a0 = a0p[q], a1 = a1p[q];
                const float c0 = cb[(size_t)(4*q + 0) * DIM];
                const float c1 = cb[(size_t)(4*q + 1) * DIM];
                const float c2 = cb[(size_t)(4*q + 2) * DIM];
                const float c3 = cb[(size_t)(4*q + 3) * DIM];
                s0 += a0.x*c0 + a0.y*c1 + a0.z*c2 + a0.w*c3;
                s1 += a1.x*c0 + a1.y*c1 + a1.z*c2 + a1.w*c3;
            }
            ctxws[(p*2 + 0) * DIM + c] = s0;
            ctxws[(p*2 + 1) * DIM + c] = s1;
        }
    }
    __syncthreads();

    {
        const int i = t & 127, pg = t >> 7, h = i >> 6;
        float acc[4] = {0.f, 0.f, 0.f, 0.f};
        for (int k = 0; k < 32; ++k) {
            const float w0 = Wkv[(4*k + 0) * 256 + 128 + i];
            const float w1 = Wkv[(4*k + 1) * 256 + 128 + i];
            const float w2 = Wkv[(4*k + 2) * 256 + 128 + i];
            const float w3 = Wkv[(4*k + 3) * 256 + 128 + i];
            #pragma unroll
            for (int pp = 0; pp < 4; ++pp) {
                const float4 cw = reinterpret_cast<const float4*>(ctxws + ((pg*4 + pp)*2 + h) * DIM)[k];
                acc[pp] += cw.x*w0 + cw.y*w1 + cw.z*w2 + cw.w*w3;
            }
        }
        #pragma unroll
        for (int pp = 0; pp < 4; ++pp) outs[(pg*4 + pp) * DIM + i] = acc[pp];
    }
    __syncthreads();

    {
        const int j = t & 127, pg = t >> 7;
        float acc[4] = {0.f, 0.f, 0.f, 0.f};
        for (int k = 0; k < 32; ++k) {
            const float w0 = Wo[(4*k + 0) * DIM + j];
            const float w1 = Wo[(4*k + 1) * DIM + j];
            const float w2 = Wo[(4*k + 2) * DIM + j];
            const float w3 = Wo[(4*k + 3) * DIM + j];
            #pragma unroll
            for (int pp = 0; pp < 4; ++pp) {
                const float4 ov = reinterpret_cast<const float4*>(outs + (pg*4 + pp) * DIM)[k];
                acc[pp] += ov.x*w0 + ov.y*w1 + ov.z*w2 + ov.w*w3;
            }
        }
        const float bj = bo[j];
        #pragma unroll
        for (int pp = 0; pp < 4; ++pp)
            out[(size_t)(gbase + pg*4 + pp) * DIM + j] = acc[pp] + bj;
    }
}

extern "C" void kernel_launch(void* const* d_in, const int* in_sizes, int n_in,
                              void* d_out, int out_size, void* d_ws, size_t ws_size,
                              hipStream_t stream) {
    const float* x   = (const float*)d_in[0];
    const float* ctx = (const float*)d_in[1];
    const float* Wq  = (const float*)d_in[2];
    const float* Wkv = (const float*)d_in[3];
    const float* Wo  = (const float*)d_in[4];
    const float* bo  = (const float*)d_in[5];
    float* out = (float*)d_out;

    const size_t needed = (size_t)(32768 + 32768) * sizeof(float);
    if (ws_size < needed) {
        dim3 grid(NPIX / PPB), block(256);
        hipLaunchKernelGGL(ppca_kernel, grid, block, 0, stream,
                           x, ctx, Wq, Wkv, Wo, bo, out);
        return;
    }

    float* Ms = (float*)d_ws;
    float* Nf = Ms + 32768;

    hipLaunchKernelGGL(fold_kernel,  dim3(256),  dim3(256), 0, stream, Wq, Wkv, Wo, Ms, Nf);
    hipLaunchKernelGGL(fused_kernel, dim3(NPIX / 16), dim3(256), 0, stream,
                       x, ctx, Ms, Nf, bo, out);
}